// Round 13
// baseline (395.883 us; speedup 1.0000x reference)
//
#include <hip/hip_runtime.h>
#include <math.h>

#define N_NODES 50000
#define N_EDGES 1600000
#define F 256
#define ALPHA 0.2f
#define NP 50048   // padded node count (multiple of 128)
#define NB 196     // coarse buckets: bucket = row >> 8 (256 rows each)
#define CAP 10240  // fixed bucket capacity (Poisson mean 8192, sigma 91 -> 22σ)
#define EPB 4096   // edges per binning block
#define NAB ((N_EDGES + EPB - 1) / EPB)  // 391
#define GEMM_BLOCKS 782  // (NP/128) * (F/128)
#define FVEC_SLOTS 2048  // grid-stride fat blocks for the projection part

typedef short bf16x8 __attribute__((ext_vector_type(8)));
typedef float f32x4 __attribute__((ext_vector_type(4)));
typedef _Float16 half4 __attribute__((ext_vector_type(4)));

__device__ __forceinline__ unsigned short f2bf(float f) {
  union { float f; unsigned u; } v; v.f = f;
  unsigned u = v.u;
  return (unsigned short)((u + 0x7fffu + ((u >> 16) & 1u)) >> 16);
}

// ---- L1: prep_w: W -> Wt bf16 transposed; wa = W @ a_halves; cb; zero gcur
__global__ __launch_bounds__(256) void prep_w(const float* __restrict__ W,
                                              const float* __restrict__ a_w,
                                              const float* __restrict__ W_b,
                                              const float* __restrict__ a_b,
                                              unsigned short* __restrict__ Wt,
                                              float* __restrict__ wa,
                                              float* __restrict__ cb,
                                              int* __restrict__ gcur) {
  if (blockIdx.x == 64) {  // zero the bucket cursors (replaces memset launch)
    if (threadIdx.x < NB) gcur[threadIdx.x] = 0;
    return;
  }
  const int lane = threadIdx.x & 63, w = threadIdx.x >> 6;
  const int k = blockIdx.x * 4 + w;  // 0..255
  float4 wv = *(const float4*)(W + (size_t)k * F + lane * 4);
  float4 a1 = *(const float4*)(a_w + lane * 4);
  float4 a2 = *(const float4*)(a_w + F + lane * 4);
  Wt[(size_t)(lane * 4 + 0) * F + k] = f2bf(wv.x);
  Wt[(size_t)(lane * 4 + 1) * F + k] = f2bf(wv.y);
  Wt[(size_t)(lane * 4 + 2) * F + k] = f2bf(wv.z);
  Wt[(size_t)(lane * 4 + 3) * F + k] = f2bf(wv.w);
  float s1 = wv.x * a1.x + wv.y * a1.y + wv.z * a1.z + wv.w * a1.w;
  float s2 = wv.x * a2.x + wv.y * a2.y + wv.z * a2.z + wv.w * a2.w;
#pragma unroll
  for (int off = 32; off > 0; off >>= 1) {
    s1 += __shfl_down(s1, off, 64);
    s2 += __shfl_down(s2, off, 64);
  }
  if (lane == 0) { wa[k] = s1; wa[F + k] = s2; }
  if (blockIdx.x == 0 && w == 0) {
    float4 b = *(const float4*)(W_b + lane * 4);
    float t1 = b.x * (a1.x + a2.x) + b.y * (a1.y + a2.y) +
               b.z * (a1.z + a2.z) + b.w * (a1.w + a2.w);
#pragma unroll
    for (int off = 32; off > 0; off >>= 1) t1 += __shfl_down(t1, off, 64);
    if (lane == 0) cb[0] = t1 + a_b[0];
  }
}

// ---- L2: fused GEMM [0,782) + binA2 [782,1173) + fvec [1173,1173+2048)
#define LDSK 72
__global__ __launch_bounds__(256) void gemm_fvec_binA2(
    const float* __restrict__ x,
    const unsigned short* __restrict__ Wt,
    const float* __restrict__ bias,
    const float* __restrict__ wa,
    const int* __restrict__ row,
    const int* __restrict__ col,
    _Float16* __restrict__ Wh,
    float* __restrict__ f_dst,
    float* __restrict__ f_row,
    int* __restrict__ gcur,
    unsigned* __restrict__ gstage) {
  __shared__ char smem[2 * 128 * LDSK * 2];  // 36864 B arena
  if (blockIdx.x < GEMM_BLOCKS) {
    // ---- GEMM part: Wh(fp16) = bf16(x) @ Wt^T + bias
    short* As = (short*)smem;
    short* Bs = As + 128 * LDSK;
    const int tid = threadIdx.x;
    const int lane = tid & 63;
    const int w = tid >> 6;
    const int wm = w >> 1, wn = w & 1;
    const int m0 = (blockIdx.x >> 1) * 128;
    const int n0 = (blockIdx.x & 1) * 128;
    f32x4 acc[4][4] = {{{0.f, 0.f, 0.f, 0.f}}};
    const int srow = tid >> 3;   // 0..31
    const int schunk = tid & 7;  // 0..7
    for (int k0 = 0; k0 < F; k0 += 64) {
#pragma unroll
      for (int i = 0; i < 4; ++i) {
        int r = i * 32 + srow;
        int gm = m0 + r; if (gm > N_NODES - 1) gm = N_NODES - 1;
        const float* src = x + (size_t)gm * F + k0 + schunk * 8;
        float4 lo = *(const float4*)src;
        float4 hi = *(const float4*)(src + 4);
        bf16x8 v;
        v[0] = (short)f2bf(lo.x); v[1] = (short)f2bf(lo.y);
        v[2] = (short)f2bf(lo.z); v[3] = (short)f2bf(lo.w);
        v[4] = (short)f2bf(hi.x); v[5] = (short)f2bf(hi.y);
        v[6] = (short)f2bf(hi.z); v[7] = (short)f2bf(hi.w);
        *(bf16x8*)&As[r * LDSK + schunk * 8] = v;
        *(bf16x8*)&Bs[r * LDSK + schunk * 8] =
            *(const bf16x8*)(Wt + (size_t)(n0 + r) * F + k0 + schunk * 8);
      }
      __syncthreads();
#pragma unroll
      for (int kk = 0; kk < 64; kk += 32) {
        const int rowsel = lane & 15;
        const int ksel = kk + (lane >> 4) * 8;
        bf16x8 af[4], bfr[4];
#pragma unroll
        for (int t = 0; t < 4; ++t) {
          af[t] = *(bf16x8*)&As[(wm * 64 + t * 16 + rowsel) * LDSK + ksel];
          bfr[t] = *(bf16x8*)&Bs[(wn * 64 + t * 16 + rowsel) * LDSK + ksel];
        }
#pragma unroll
        for (int mi = 0; mi < 4; ++mi)
#pragma unroll
          for (int nj = 0; nj < 4; ++nj)
            acc[mi][nj] = __builtin_amdgcn_mfma_f32_16x16x32_bf16(
                af[mi], bfr[nj], acc[mi][nj], 0, 0, 0);
      }
      __syncthreads();
    }
    const int crow = (lane >> 4) * 4;
    const int ccol = lane & 15;
#pragma unroll
    for (int nj = 0; nj < 4; ++nj) {
      int gc = n0 + wn * 64 + nj * 16 + ccol;
      float bv = bias[gc];
#pragma unroll
      for (int mi = 0; mi < 4; ++mi) {
        int gr = m0 + wm * 64 + mi * 16 + crow;
#pragma unroll
        for (int r = 0; r < 4; ++r)
          Wh[(size_t)(gr + r) * F + gc] = (_Float16)(acc[mi][nj][r] + bv);
      }
    }
    return;
  }
  if (blockIdx.x < GEMM_BLOCKS + NAB) {
    // ---- binA2 part
    int* h = (int*)smem;
    int* lofs = h + NB;
    int* lcur = lofs + NB;
    int* gb = lcur + NB;
    unsigned* stage = (unsigned*)(gb + NB);  // EPB entries
    const int t = threadIdx.x;
    for (int i = t; i < NB; i += 256) { h[i] = 0; lcur[i] = 0; }
    __syncthreads();
    const int base = (blockIdx.x - GEMM_BLOCKS) * EPB;
    const int cnt = min(EPB, N_EDGES - base);
#pragma unroll
    for (int j = 0; j < 16; ++j) {
      int k = base + j * 256 + t;
      if (k < N_EDGES) atomicAdd(&h[row[k] >> 8], 1);
    }
    __syncthreads();
    if (t == 0) {
      int run = 0;
      for (int i = 0; i < NB; ++i) { lofs[i] = run; run += h[i]; }
    }
    __syncthreads();
    if (t < NB && h[t] > 0) gb[t] = atomicAdd(&gcur[t], h[t]);
    __syncthreads();
#pragma unroll
    for (int j = 0; j < 16; ++j) {
      int k = base + j * 256 + t;
      if (k < N_EDGES) {
        int r = row[k], b = r >> 8;
        int lp = lofs[b] + atomicAdd(&lcur[b], 1);
        stage[lp] = ((unsigned)b << 24) | ((unsigned)(r & 255) << 16) |
                    (unsigned)col[k];
      }
    }
    __syncthreads();
#pragma unroll
    for (int j = 0; j < 16; ++j) {
      int s = j * 256 + t;
      if (s < cnt) {
        unsigned wv = stage[s];
        int b = wv >> 24;
        gstage[(size_t)b * CAP + gb[b] + (s - lofs[b])] = wv & 0x00FFFFFFu;
      }
    }
    return;
  }
  // ---- fvec part: grid-stride fat blocks (4 nodes/iter/block)
  const int lane = threadIdx.x & 63, w = threadIdx.x >> 6;
  const int slot = blockIdx.x - GEMM_BLOCKS - NAB;
  float4 v1 = *(const float4*)(wa + lane * 4);
  float4 v2 = *(const float4*)(wa + F + lane * 4);
  for (int node = slot * 4 + w; node < N_NODES; node += FVEC_SLOTS * 4) {
    float4 xv = *(const float4*)(x + (size_t)node * F + lane * 4);
    float s1 = xv.x * v1.x + xv.y * v1.y + xv.z * v1.z + xv.w * v1.w;
    float s2 = xv.x * v2.x + xv.y * v2.y + xv.z * v2.z + xv.w * v2.w;
#pragma unroll
    for (int off = 32; off > 0; off >>= 1) {
      s1 += __shfl_down(s1, off, 64);
      s2 += __shfl_down(s2, off, 64);
    }
    if (lane == 0) { f_dst[node] = s1; f_row[node] = s2; }
  }
}

// ---- L3: binB (512 thr): sort each bucket's edges by key
// (rowgroup g = lr>>6, wave w = lr&3, colbin = c>>9) -> 8 B entries
// (col | lr6<<16, weight_fp32); wofs[(b*4+g)*4+w] = {start,end}.
__global__ __launch_bounds__(512) void binB(const int* __restrict__ gcur,
                                            const unsigned* __restrict__ gstage,
                                            const float* __restrict__ f_dst,
                                            const float* __restrict__ f_row,
                                            const float* __restrict__ cb,
                                            int2* __restrict__ wofs,
                                            float* __restrict__ inv_denom,
                                            uint2* __restrict__ csr2) {
  __shared__ int cnt2[2048], cur2[2048];
  __shared__ int psum[512];
  __shared__ float dsum[256];
  const int t = threadIdx.x;
  const int b = blockIdx.x;
  for (int i = t; i < 2048; i += 512) cnt2[i] = 0;
  if (t < 256) dsum[t] = 0.f;
  __syncthreads();
  const int nb = gcur[b];
  const int start = b * CAP;
  const float cbs = cb[0];
  for (int s = t; s < nb; s += 512) {
    unsigned wv = gstage[start + s];
    int lr = (wv >> 16) & 255, c = wv & 0xFFFF;
    int key = ((lr >> 6) << 9) | ((lr & 3) << 7) | (c >> 9);
    atomicAdd(&cnt2[key], 1);
  }
  __syncthreads();
  const int lbase = t * 4;
  int l0 = cnt2[lbase], l1 = cnt2[lbase + 1], l2 = cnt2[lbase + 2],
      l3 = cnt2[lbase + 3];
  psum[t] = l0 + l1 + l2 + l3;
  __syncthreads();
  if (t == 0) {
    int run = 0;
    for (int i = 0; i < 512; ++i) { int v = psum[i]; psum[i] = run; run += v; }
  }
  __syncthreads();
  {
    int base = start + psum[t];
    cur2[lbase] = base;
    cur2[lbase + 1] = base + l0;
    cur2[lbase + 2] = base + l0 + l1;
    cur2[lbase + 3] = base + l0 + l1 + l2;
  }
  __syncthreads();
  if (t < 16) {  // (g,w) range boundaries, pre-placement cursor values
    int k = ((t >> 2) << 9) | ((t & 3) << 7);
    int s0 = cur2[k];
    int e0 = (t == 15) ? (start + nb) : cur2[k + 128];
    wofs[b * 16 + t] = make_int2(s0, e0);
  }
  __syncthreads();
  for (int s = t; s < nb; s += 512) {
    unsigned wv = gstage[start + s];
    int lr = (wv >> 16) & 255, c = wv & 0xFFFF;
    float ev = f_dst[c] + f_row[(b << 8) + lr] + cbs;
    ev = ev > 0.f ? ev : ALPHA * ev;
    float ex = __expf(ev);
    int key = ((lr >> 6) << 9) | ((lr & 3) << 7) | (c >> 9);
    int p = atomicAdd(&cur2[key], 1);
    csr2[p] = make_uint2((unsigned)c | ((unsigned)(lr & 63) << 16),
                         __float_as_uint(ex));
    atomicAdd(&dsum[lr], ex);
  }
  __syncthreads();
  if (t < 256) {
    int g = (b << 8) + t;
    if (g < N_NODES) inv_denom[g] = dsum[t] > 0.f ? (1.0f / dsum[t]) : 0.f;
  }
}

// ---- L4: push-mode SpMM: block = 64 output rows in 64 KB LDS fp32 acc.
// Each wave processes its col-sorted edge range (rows lr6&3==w -> no races).
// All blocks sweep cols in phase -> Wh gathers hit a small L2 window.
__global__ __launch_bounds__(256) void gat_push(const int2* __restrict__ wofs,
                                                const uint2* __restrict__ csr2,
                                                const float* __restrict__ inv_denom,
                                                const _Float16* __restrict__ Wh,
                                                float* __restrict__ out) {
  __shared__ float acc[64 * 256];  // 64 KB -> 2 blocks/CU
  const int t = threadIdx.x;
  float4* a4 = (float4*)acc;
  for (int i = t; i < 64 * 64; i += 256)
    a4[i] = make_float4(0.f, 0.f, 0.f, 0.f);
  __syncthreads();
  const int lane = t & 63, w = t >> 6;
  const int2 se = wofs[blockIdx.x * 4 + w];
  const int s0 = se.x, e0 = se.y;
  const half4* Wh4 = (const half4*)Wh;
  for (int p = s0; p < e0; p += 4) {
    uint2 en[4];
#pragma unroll
    for (int j = 0; j < 4; ++j) {
      int q = p + j;
      en[j] = csr2[q < e0 ? q : s0];
    }
    half4 v[4];
#pragma unroll
    for (int j = 0; j < 4; ++j)
      v[j] = Wh4[(size_t)(en[j].x & 0xFFFFu) * 64 + lane];
#pragma unroll
    for (int j = 0; j < 4; ++j) {
      float wgt = (p + j < e0) ? __uint_as_float(en[j].y) : 0.f;
      int lr6 = (en[j].x >> 16) & 63;
      float* ap = &acc[lr6 * 256 + lane * 4];
      ap[0] += wgt * (float)v[j][0];
      ap[1] += wgt * (float)v[j][1];
      ap[2] += wgt * (float)v[j][2];
      ap[3] += wgt * (float)v[j][3];
    }
  }
  __syncthreads();
  const int rowbase = ((blockIdx.x >> 2) << 8) + ((blockIdx.x & 3) << 6);
#pragma unroll
  for (int k = 0; k < 16; ++k) {
    int i = k * 256 + t;
    int grow = rowbase + (i >> 6);
    if (grow < N_NODES) {
      float inv = inv_denom[grow];
      float4 v = a4[i];
      v.x = fmaxf(v.x * inv, 0.f); v.y = fmaxf(v.y * inv, 0.f);
      v.z = fmaxf(v.z * inv, 0.f); v.w = fmaxf(v.w * inv, 0.f);
      ((float4*)out)[(size_t)grow * 64 + (i & 63)] = v;
    }
  }
}

extern "C" void kernel_launch(void* const* d_in, const int* in_sizes, int n_in,
                              void* d_out, int out_size, void* d_ws, size_t ws_size,
                              hipStream_t stream) {
  const float* x   = (const float*)d_in[0];
  const float* W_w = (const float*)d_in[1];
  const float* W_b = (const float*)d_in[2];
  const float* a_w = (const float*)d_in[3];
  const float* a_b = (const float*)d_in[4];
  const int*   row = (const int*)d_in[5];
  const int*   col = (const int*)d_in[6];
  float* out = (float*)d_out;

  float* ws = (float*)d_ws;
  size_t off = 0;
  _Float16* Wh = (_Float16*)(ws + off); off += (size_t)NP * F / 2;       // fp16
  unsigned short* Wt = (unsigned short*)(ws + off); off += (F * F) / 2;  // bf16
  float* wa = ws + off;            off += 2 * F;
  float* cb = ws + off;            off += 8;
  float* f_dst = ws + off;         off += NP;
  float* f_row = ws + off;         off += NP;
  int* gcur = (int*)(ws + off);    off += NB;
  int2* wofs = (int2*)(ws + off);  off += 2 * NB * 16;
  float* inv_denom = (float*)(ws + off); off += NP;
  unsigned* gstage = (unsigned*)(ws + off); off += (size_t)NB * CAP;
  uint2* csr2 = (uint2*)(ws + off); off += 2 * (size_t)NB * CAP;
  (void)ws_size; (void)in_sizes; (void)n_in; (void)out_size;

  hipLaunchKernelGGL(prep_w, dim3(65), dim3(256), 0, stream, W_w, a_w, W_b,
                     a_b, Wt, wa, cb, gcur);
  hipLaunchKernelGGL(gemm_fvec_binA2, dim3(GEMM_BLOCKS + NAB + FVEC_SLOTS),
                     dim3(256), 0, stream, x, Wt, W_b, wa, row, col, Wh,
                     f_dst, f_row, gcur, gstage);
  hipLaunchKernelGGL(binB, dim3(NB), dim3(512), 0, stream, gcur, gstage,
                     f_dst, f_row, cb, wofs, inv_denom, csr2);
  hipLaunchKernelGGL(gat_push, dim3(NB * 4), dim3(256), 0, stream, wofs,
                     csr2, inv_denom, Wh, out);
}